// Round 5
// baseline (555.469 us; speedup 1.0000x reference)
//
#include <hip/hip_runtime.h>
#include <math.h>

#define N_GT 256
#define M_PR 1024
#define LG   91
#define CPL  16   // columns per lane (64 lanes * 16 = 1024)

// ---------------------------------------------------------------------------
// Kernel 1: cost[i][j] = sqrt(|cgt_i - cpred_j|^2) + sum_l |lgt_i - lpred_j|
// One block per gt row i; fused rowmin/rowarg for the greedy init.
// ---------------------------------------------------------------------------
__global__ __launch_bounds__(256) void cost_kernel(
    const float* __restrict__ cgt, const float* __restrict__ cpred,
    const float* __restrict__ lgt, const float* __restrict__ lpred,
    float* __restrict__ cost, float* __restrict__ rowmin, int* __restrict__ rowarg)
{
    __shared__ float sg[LG];
    __shared__ float gx, gy;
    __shared__ float wmin[4];
    __shared__ int   warg[4];
    const int i   = blockIdx.x;
    const int tid = threadIdx.x;
    if (tid < LG) sg[tid] = lgt[i * LG + tid];
    if (tid == 0) { gx = cgt[2 * i]; gy = cgt[2 * i + 1]; }
    __syncthreads();
    float bv = 1e30f; int bj = 0;
    for (int j = tid; j < M_PR; j += 256) {
        float dx = gx - cpred[2 * j];
        float dy = gy - cpred[2 * j + 1];
        float cd = sqrtf(dx * dx + dy * dy);
        const float* lp = lpred + j * LG;
        float s = 0.f;
        #pragma unroll 7
        for (int l = 0; l < LG; ++l) s += fabsf(sg[l] - lp[l]);
        float cv = cd + s;
        cost[i * M_PR + j] = cv;
        if (cv < bv) { bv = cv; bj = j; }
    }
    const int lane = tid & 63, wid = tid >> 6;
    #pragma unroll
    for (int off = 1; off < 64; off <<= 1) {
        float ov = __shfl_xor(bv, off, 64);
        int   oj = __shfl_xor(bj, off, 64);
        if (ov < bv || (ov == bv && oj < bj)) { bv = ov; bj = oj; }
    }
    if (lane == 0) { wmin[wid] = bv; warg[wid] = bj; }
    __syncthreads();
    if (tid == 0) {
        for (int w = 1; w < 4; ++w)
            if (wmin[w] < bv || (wmin[w] == bv && warg[w] < bj)) { bv = wmin[w]; bj = warg[w]; }
        rowmin[i] = bv; rowarg[i] = bj;
    }
}

// ---------------------------------------------------------------------------
// Kernel 2: LAPJV-style LSA, single wave (64 lanes).
// Phase 1: greedy row->argmin claim (smallest row wins), u[i]=rowmin, v=0.
// Phase 2: augmenting row reduction (LAPJV): min1/min2 scan, v[j1] -= gap,
//          displace owner (immediate reprocess on strict, next pass on tie).
//          2 passes + visit cap; preserves feasibility + CS exactly (f64).
// Phase 3: shortest-augmenting-path (Dijkstra) for remaining free rows,
//          zero barriers in the inner loop, per-column state in registers,
//          absolute-distance form + deferred dual flush.
// Unique optimum => output identical to the reference.
// Output (f32): [0..255]=row, [256..511]=col, [512]=cost.
// ---------------------------------------------------------------------------
__global__ __launch_bounds__(64) void lsa_kernel(
    const float* __restrict__ cost,
    const float* __restrict__ rowmin, const int* __restrict__ rowarg,
    const float* __restrict__ cgt, const float* __restrict__ cpred,
    float* __restrict__ out)
{
    __shared__ double u[N_GT + 1];
    __shared__ int    p[M_PR + 1];
    __shared__ int    pmin[M_PR + 1];
    __shared__ int    way[M_PR + 1];
    __shared__ int    rcol[N_GT + 1];
    __shared__ int    freeA[N_GT], freeB[N_GT];
    __shared__ int    colarr[N_GT];

    const int lane = threadIdx.x;

    double v[CPL], A[CPL], markD[CPL];
    int    bw[CPL];

    for (int j = lane; j <= M_PR; j += 64) { p[j] = 0; pmin[j] = 0x7FFFFFFF; }
    for (int r = lane; r < N_GT; r += 64) colarr[r] = 0;
    if (lane == 0) { u[0] = 0.0; rcol[0] = 0; }
    #pragma unroll
    for (int k = 0; k < CPL; ++k) { v[k] = 0.0; bw[k] = 0; markD[k] = 0.0; }
    __syncthreads();

    // ---- Phase 1: greedy claim ----
    #pragma unroll
    for (int g = 0; g < 4; ++g) {
        int i = g * 64 + lane;                 // 0-based row
        u[i + 1] = (double)rowmin[i];
        atomicMin(&pmin[rowarg[i] + 1], i + 1);
    }
    __syncthreads();
    for (int j = lane + 1; j <= M_PR; j += 64)
        p[j] = (pmin[j] == 0x7FFFFFFF) ? 0 : pmin[j];
    #pragma unroll
    for (int g = 0; g < 4; ++g) {
        int i = g * 64 + lane;
        int jc = rowarg[i] + 1;
        rcol[i + 1] = (pmin[jc] == i + 1) ? jc : 0;
    }
    __syncthreads();
    int nfree = 0;
    #pragma unroll
    for (int g = 0; g < 4; ++g) {
        int i = g * 64 + lane;
        bool um = (rcol[i + 1] == 0);
        unsigned long long mask = __ballot(um);
        int pos = nfree + __popcll(mask & ((1ull << lane) - 1ull));
        if (um) freeA[pos] = i + 1;
        nfree += __popcll(mask);
    }
    __syncthreads();

    // ---- Phase 2: augmenting row reduction (LAPJV), 2 passes ----
    int visits = 0;
    for (int pass = 0; pass < 2; ++pass) {
        int kIdx = 0, nNext = 0;
        while (kIdx < nfree) {
            if (++visits > 2048) break;        // safety cap (uniform)
            const int i = freeA[kIdx++];       // 1-based free row (broadcast)
            const float* crow = cost + (size_t)(i - 1) * M_PR;
            // per-lane (min1,col1,min2,col2) over 16 cols of h = c - v
            double m1 = 1e18, m2 = 1e18; int c1 = 0, c2 = 0;
            #pragma unroll
            for (int k = 0; k < CPL; ++k) {
                int col = lane + 1 + 64 * k;
                double h = (double)crow[col - 1] - v[k];
                bool lt1 = h < m1;
                bool lt2 = h < m2;
                double nm2 = lt1 ? m1 : (lt2 ? h : m2);
                int    nc2 = lt1 ? c1 : (lt2 ? col : c2);
                m1 = lt1 ? h : m1; c1 = lt1 ? col : c1;
                m2 = nm2; c2 = nc2;
            }
            // butterfly merge of sorted-2 lists (symmetric, deterministic)
            #pragma unroll
            for (int off = 1; off < 64; off <<= 1) {
                double om1 = __shfl_xor(m1, off, 64); int oc1 = __shfl_xor(c1, off, 64);
                double om2 = __shfl_xor(m2, off, 64); int oc2 = __shfl_xor(c2, off, 64);
                bool mineFirst = (m1 < om1) || (m1 == om1 && c1 < oc1);
                if (mineFirst) {
                    if (om1 < m2) { m2 = om1; c2 = oc1; }
                } else {
                    double t2; int tc2;
                    if (m1 < om2) { t2 = m1; tc2 = c1; } else { t2 = om2; tc2 = oc2; }
                    m1 = om1; c1 = oc1; m2 = t2; c2 = tc2;
                }
            }
            int j1 = c1; const double u1 = m1, u2 = m2;
            int own = p[j1];                   // broadcast
            const bool strict = (u1 < u2);
            if (strict) {
                double du = u2 - u1;
                #pragma unroll
                for (int k = 0; k < CPL; ++k)
                    v[k] -= (lane + 1 + 64 * k == j1) ? du : 0.0;
            } else if (own > 0) {
                j1 = c2; own = p[j1];          // tie: try second-min col
            }
            if (lane == 0) {
                u[i] = u2;                     // tight at assigned col
                p[j1] = i;
                rcol[i] = j1;
                if (own > 0) rcol[own] = 0;
            }
            if (own > 0) {
                if (strict) { kIdx -= 1; if (lane == 0) freeA[kIdx] = own; }
                else        { if (lane == 0) freeB[nNext] = own; nNext += 1; }
            }
            __syncthreads();
        }
        for (int t = lane; t < nNext; t += 64) freeA[t] = freeB[t];
        nfree = nNext;
        __syncthreads();
    }

    // rebuild final free list from rcol (covers cap-break leftovers too)
    int nf2 = 0;
    #pragma unroll
    for (int g = 0; g < 4; ++g) {
        int i = g * 64 + lane;
        bool um = (rcol[i + 1] == 0);
        unsigned long long mask = __ballot(um);
        int pos = nf2 + __popcll(mask & ((1ull << lane) - 1ull));
        if (um) freeA[pos] = i + 1;
        nf2 += __popcll(mask);
    }
    __syncthreads();

    // ---- Phase 3: shortest augmenting path for remaining free rows ----
    for (int t = 0; t < nf2; ++t) {
        const int i = freeA[t];                // 1-based free row
        #pragma unroll
        for (int k = 0; k < CPL; ++k) A[k] = 1e18;
        unsigned usedmask = 0u;
        double D  = 0.0;
        int    j0 = 0;
        int    i0 = i;
        while (true) {
            const float* crow = cost + (size_t)(i0 - 1) * M_PR;
            double ui   = u[i0];
            double base2 = ui - D;

            double   bestA  = 1e18;
            unsigned bestjw = 0xFFFFFFFFu;
            #pragma unroll
            for (int k = 0; k < CPL; ++k) {
                const int col = lane + 1 + 64 * k;
                double c = (double)crow[col - 1];
                bool isj0 = (col == j0);
                if (isj0) { usedmask |= (1u << k); markD[k] = D; }
                bool unused = ((usedmask >> k) & 1u) == 0u;
                double cur = c - base2 - v[k];
                bool upd = unused && (cur < A[k]);
                A[k]  = upd ? cur : A[k];
                bw[k] = upd ? j0  : bw[k];
                if (unused && A[k] < bestA) {
                    bestA  = A[k];
                    bestjw = ((unsigned)col << 11) | (unsigned)bw[k];
                }
            }
            #pragma unroll
            for (int off = 1; off < 64; off <<= 1) {
                double   oA  = __shfl_xor(bestA, off, 64);
                unsigned ojw = (unsigned)__shfl_xor((int)bestjw, off, 64);
                bool b = (oA < bestA) || (oA == bestA && ojw < bestjw);
                bestA  = b ? oA  : bestA;
                bestjw = b ? ojw : bestjw;
            }
            D = bestA;
            int j1 = (int)(bestjw >> 11);
            int w1 = (int)(bestjw & 0x7FFu);
            if (lane == 0) way[j1] = w1;
            int pj = p[j1];
            j0 = j1;
            if (pj == 0) break;
            i0 = pj;
        }
        if (lane == 0) u[i] += D;
        #pragma unroll
        for (int k = 0; k < CPL; ++k) {
            if ((usedmask >> k) & 1u) {
                const int col = lane + 1 + 64 * k;
                double adj = D - markD[k];
                v[k] -= adj;
                int r = p[col];
                u[r] += adj;
            }
        }
        __syncthreads();
        if (lane == 0) {
            int jj = j0;
            while (jj != 0) {
                int jp = way[jj];
                p[jj] = (jp == 0) ? i : p[jp];
                jj = jp;
            }
        }
        __syncthreads();
    }

    // ---- gather + outputs ----
    #pragma unroll
    for (int k = 0; k < CPL; ++k) {
        int j  = lane + 1 + 64 * k;
        int pr = p[j];
        if (pr > 0) colarr[pr - 1] = j - 1;
    }
    __syncthreads();

    for (int idx = lane; idx < N_GT; idx += 64) {
        out[idx]        = (float)idx;
        out[N_GT + idx] = (float)colarr[idx];
    }
    float s = 0.f;
    for (int idx = lane; idx < N_GT; idx += 64) {
        int c = colarr[idx];
        c = (c < 0) ? 0 : (c >= M_PR ? M_PR - 1 : c);
        float dx = cgt[2 * idx]     - cpred[2 * c];
        float dy = cgt[2 * idx + 1] - cpred[2 * c + 1];
        s += sqrtf(dx * dx + dy * dy);
    }
    #pragma unroll
    for (int off = 1; off < 64; off <<= 1) s += __shfl_xor(s, off, 64);
    if (lane == 0) out[2 * N_GT] = s;
}

extern "C" void kernel_launch(void* const* d_in, const int* in_sizes, int n_in,
                              void* d_out, int out_size, void* d_ws, size_t ws_size,
                              hipStream_t stream)
{
    const float* cgt   = (const float*)d_in[0];   // (256, 2)
    const float* cpred = (const float*)d_in[1];   // (1024, 2)
    const float* lgt   = (const float*)d_in[2];   // (256, 91)
    const float* lpred = (const float*)d_in[3];   // (1024, 91)
    float* out  = (float*)d_out;                  // 513 floats

    char* ws = (char*)d_ws;
    float* cost   = (float*)ws;                        // 1 MB
    float* rowmin = (float*)(ws + (size_t)N_GT * M_PR * 4);          // 1 KB
    int*   rowarg = (int*)  (ws + (size_t)N_GT * M_PR * 4 + N_GT*4); // 1 KB

    cost_kernel<<<N_GT, 256, 0, stream>>>(cgt, cpred, lgt, lpred, cost, rowmin, rowarg);
    lsa_kernel<<<1, 64, 0, stream>>>(cost, rowmin, rowarg, cgt, cpred, out);
}

// Round 8
// 421.988 us; speedup vs baseline: 1.3163x; 1.3163x over previous
//
#include <hip/hip_runtime.h>
#include <math.h>

#define N_GT 256
#define M_PR 1024
#define LG   91
#define CPL  16   // columns per lane (64 lanes * 16 = 1024)

// Order-exact monotone map: double -> uint64 (increasing), incl. negatives/inf.
static __device__ __forceinline__ unsigned long long d2key(double x) {
    unsigned long long b = (unsigned long long)__double_as_longlong(x);
    return (b & 0x8000000000000000ull) ? ~b : (b | 0x8000000000000000ull);
}
static __device__ __forceinline__ double key2d(unsigned long long k) {
    unsigned long long b = (k & 0x8000000000000000ull) ? (k ^ 0x8000000000000000ull) : ~k;
    return __longlong_as_double((long long)b);
}

// DPP wave64 min-reduce stage on 96-bit lexicographic key (khi, klo, kcw).
// update_dpp(old=x, src=x): masked/invalid lanes keep old -> identity for min.
#define DPP_STAGE(hi, lo, cw, CTRL, RM, BM) do { \
    unsigned _ohi = (unsigned)__builtin_amdgcn_update_dpp((int)(hi), (int)(hi), CTRL, RM, BM, false); \
    unsigned _olo = (unsigned)__builtin_amdgcn_update_dpp((int)(lo), (int)(lo), CTRL, RM, BM, false); \
    unsigned _ocw = (unsigned)__builtin_amdgcn_update_dpp((int)(cw), (int)(cw), CTRL, RM, BM, false); \
    bool _lt = (_ohi < (hi)) || (_ohi == (hi) && ((_olo < (lo)) || (_olo == (lo) && _ocw < (cw)))); \
    (hi) = _lt ? _ohi : (hi); (lo) = _lt ? _olo : (lo); (cw) = _lt ? _ocw : (cw); \
} while (0)

// ---------------------------------------------------------------------------
// Kernel 1: cost[i][j] = sqrt(|cgt_i - cpred_j|^2) + sum_l |lgt_i - lpred_j|
// Fused rowmin/rowarg (first-occurrence argmin) for the greedy init.
// ---------------------------------------------------------------------------
__global__ __launch_bounds__(256) void cost_kernel(
    const float* __restrict__ cgt, const float* __restrict__ cpred,
    const float* __restrict__ lgt, const float* __restrict__ lpred,
    float* __restrict__ cost, float* __restrict__ rowmin, int* __restrict__ rowarg)
{
    __shared__ float sg[LG];
    __shared__ float gx, gy;
    __shared__ float wmin[4];
    __shared__ int   warg[4];
    const int i   = blockIdx.x;
    const int tid = threadIdx.x;
    if (tid < LG) sg[tid] = lgt[i * LG + tid];
    if (tid == 0) { gx = cgt[2 * i]; gy = cgt[2 * i + 1]; }
    __syncthreads();
    float bv = 1e30f; int bj = 0;
    for (int j = tid; j < M_PR; j += 256) {
        float dx = gx - cpred[2 * j];
        float dy = gy - cpred[2 * j + 1];
        float cd = sqrtf(dx * dx + dy * dy);
        const float* lp = lpred + j * LG;
        float s = 0.f;
        #pragma unroll 7
        for (int l = 0; l < LG; ++l) s += fabsf(sg[l] - lp[l]);
        float cv = cd + s;
        cost[i * M_PR + j] = cv;
        if (cv < bv) { bv = cv; bj = j; }
    }
    const int lane = tid & 63, wid = tid >> 6;
    #pragma unroll
    for (int off = 1; off < 64; off <<= 1) {
        float ov = __shfl_xor(bv, off, 64);
        int   oj = __shfl_xor(bj, off, 64);
        if (ov < bv || (ov == bv && oj < bj)) { bv = ov; bj = oj; }
    }
    if (lane == 0) { wmin[wid] = bv; warg[wid] = bj; }
    __syncthreads();
    if (tid == 0) {
        for (int w = 1; w < 4; ++w)
            if (wmin[w] < bv || (wmin[w] == bv && warg[w] < bj)) { bv = wmin[w]; bj = warg[w]; }
        rowmin[i] = bv; rowarg[i] = bj;
    }
}

// ---------------------------------------------------------------------------
// Kernel 2: JV LSA (round-4 validated semantics: greedy claim u=rowmin, v=0,
// then exact Dijkstra per unmatched row). Single wave, zero barriers in the
// inner loop; per-column state in registers; absolute-distance form +
// deferred dual flush; DPP min-reduce on an order-exact 96-bit key;
// parallel augmentation apply.
// Output (f32): [0..255]=row, [256..511]=col, [512]=cost.
// ---------------------------------------------------------------------------
__global__ __launch_bounds__(64) void lsa_kernel(
    const float* __restrict__ cost,
    const float* __restrict__ rowmin, const int* __restrict__ rowarg,
    const float* __restrict__ cgt, const float* __restrict__ cpred,
    float* __restrict__ out)
{
    __shared__ double u[N_GT + 1];
    __shared__ int    p[M_PR + 1];
    __shared__ int    pmin[M_PR + 1];
    __shared__ int    way[M_PR + 1];
    __shared__ int    pathbuf[N_GT + 8];
    __shared__ int    pathlen_s;
    __shared__ int    freeA[N_GT];
    __shared__ int    colarr[N_GT];

    const int lane = threadIdx.x;

    double v[CPL], A[CPL], markD[CPL];
    int    bw[CPL];

    for (int j = lane; j <= M_PR; j += 64) { p[j] = 0; pmin[j] = 0x7FFFFFFF; }
    for (int r = lane; r < N_GT; r += 64) colarr[r] = 0;
    if (lane == 0) u[0] = 0.0;
    #pragma unroll
    for (int k = 0; k < CPL; ++k) { v[k] = 0.0; bw[k] = 0; markD[k] = 0.0; }
    __syncthreads();

    // ---- greedy claim: row -> its argmin col, smallest row wins ----
    #pragma unroll
    for (int g = 0; g < 4; ++g) {
        int i = g * 64 + lane;                 // 0-based row
        u[i + 1] = (double)rowmin[i];
        atomicMin(&pmin[rowarg[i] + 1], i + 1);
    }
    __syncthreads();
    for (int j = lane + 1; j <= M_PR; j += 64)
        p[j] = (pmin[j] == 0x7FFFFFFF) ? 0 : pmin[j];
    int nfree = 0;
    #pragma unroll
    for (int g = 0; g < 4; ++g) {
        int i = g * 64 + lane;
        bool um = (pmin[rowarg[i] + 1] != i + 1);
        unsigned long long mask = __ballot(um);
        int pos = nfree + __popcll(mask & ((1ull << lane) - 1ull));
        if (um) freeA[pos] = i + 1;            // 1-based row
        nfree += __popcll(mask);
    }
    __syncthreads();

    // ---- shortest augmenting path per free row ----
    for (int t = 0; t < nfree; ++t) {
        const int i = freeA[t];
        #pragma unroll
        for (int k = 0; k < CPL; ++k) A[k] = 1e18;
        unsigned usedmask = 0u;
        double D  = 0.0;
        int    j0 = 0;
        int    i0 = i;
        while (true) {
            const float* crow = cost + (size_t)(i0 - 1) * M_PR;
            double ui = u[i0];                  // LDS broadcast (search-start value)
            float cf[CPL];
            #pragma unroll
            for (int k = 0; k < CPL; ++k) cf[k] = crow[lane + 64 * k];
            double base2 = ui - D;

            double   bA  = __builtin_inf();
            unsigned bcw = 0xFFFFFFFFu;
            #pragma unroll
            for (int k = 0; k < CPL; ++k) {
                const int col = lane + 1 + 64 * k;
                if (col == j0) {                // settle previous winner
                    usedmask |= (1u << k);
                    markD[k] = D;
                    A[k] = __builtin_inf();
                }
                bool unused = ((usedmask >> k) & 1u) == 0u;
                double cur = (double)cf[k] - base2 - v[k];
                bool upd = unused && (cur < A[k]);
                A[k]  = upd ? cur : A[k];
                bw[k] = upd ? j0  : bw[k];
                unsigned cwk = ((unsigned)col << 11) | (unsigned)bw[k];
                bool tk = (A[k] < bA);          // strict: first (smallest col) kept
                bA  = tk ? A[k] : bA;
                bcw = tk ? cwk  : bcw;
            }
            // order-exact 96-bit DPP min-reduce -> lane 63
            unsigned long long key = d2key(bA);
            unsigned khi = (unsigned)(key >> 32);
            unsigned klo = (unsigned)(key & 0xFFFFFFFFull);
            unsigned kcw = bcw;
            DPP_STAGE(khi, klo, kcw, 0x111, 0xf, 0xf);  // row_shr:1
            DPP_STAGE(khi, klo, kcw, 0x112, 0xf, 0xf);  // row_shr:2
            DPP_STAGE(khi, klo, kcw, 0x114, 0xf, 0xe);  // row_shr:4
            DPP_STAGE(khi, klo, kcw, 0x118, 0xf, 0xc);  // row_shr:8
            DPP_STAGE(khi, klo, kcw, 0x142, 0xa, 0xf);  // row_bcast:15
            DPP_STAGE(khi, klo, kcw, 0x143, 0xc, 0xf);  // row_bcast:31
            unsigned rhi = (unsigned)__builtin_amdgcn_readlane((int)khi, 63);
            unsigned rlo = (unsigned)__builtin_amdgcn_readlane((int)klo, 63);
            unsigned rcw = (unsigned)__builtin_amdgcn_readlane((int)kcw, 63);
            D = key2d(((unsigned long long)rhi << 32) | (unsigned long long)rlo);
            int j1 = (int)(rcw >> 11);
            int w1 = (int)(rcw & 2047u);
            if (lane == 0) way[j1] = w1;
            int pj = p[j1];                     // LDS broadcast
            j0 = j1;
            if (pj == 0) break;                 // reached a free column
            i0 = pj;
        }
        // ---- deferred dual flush (pre-augmentation p) ----
        if (lane == 0) u[i] += D;               // virtual col 0: markD = 0
        #pragma unroll
        for (int k = 0; k < CPL; ++k) {
            if ((usedmask >> k) & 1u) {
                double adj = D - markD[k];
                v[k] -= adj;
                int r = p[lane + 1 + 64 * k];   // distinct rows, no race
                u[r] += adj;
            }
        }
        __syncthreads();
        // ---- augmentation: collect path, then parallel apply (old reads) ----
        if (lane == 0) {
            int L = 0, jj = j0;
            while (jj != 0) { pathbuf[L++] = jj; jj = way[jj]; }
            pathlen_s = L;
        }
        __syncthreads();
        const int L = pathlen_s;                // L <= 257
        int d0=-1,s0=0,d1=-1,s1=0,d2=-1,s2=0,d3=-1,s3=0,d4=-1,s4=0;
        { int tt = lane;       if (tt < L) { d0 = pathbuf[tt]; s0 = (tt == L-1) ? i : p[pathbuf[tt+1]]; } }
        { int tt = lane +  64; if (tt < L) { d1 = pathbuf[tt]; s1 = (tt == L-1) ? i : p[pathbuf[tt+1]]; } }
        { int tt = lane + 128; if (tt < L) { d2 = pathbuf[tt]; s2 = (tt == L-1) ? i : p[pathbuf[tt+1]]; } }
        { int tt = lane + 192; if (tt < L) { d3 = pathbuf[tt]; s3 = (tt == L-1) ? i : p[pathbuf[tt+1]]; } }
        { int tt = lane + 256; if (tt < L) { d4 = pathbuf[tt]; s4 = (tt == L-1) ? i : p[pathbuf[tt+1]]; } }
        __syncthreads();
        if (d0 >= 0) p[d0] = s0;
        if (d1 >= 0) p[d1] = s1;
        if (d2 >= 0) p[d2] = s2;
        if (d3 >= 0) p[d3] = s3;
        if (d4 >= 0) p[d4] = s4;
        __syncthreads();
    }

    // ---- gather + outputs ----
    #pragma unroll
    for (int k = 0; k < CPL; ++k) {
        int j  = lane + 1 + 64 * k;
        int pr = p[j];
        if (pr > 0) colarr[pr - 1] = j - 1;
    }
    __syncthreads();

    for (int idx = lane; idx < N_GT; idx += 64) {
        out[idx]        = (float)idx;
        out[N_GT + idx] = (float)colarr[idx];
    }
    float s = 0.f;
    for (int idx = lane; idx < N_GT; idx += 64) {
        int c = colarr[idx];
        c = (c < 0) ? 0 : (c >= M_PR ? M_PR - 1 : c);
        float dx = cgt[2 * idx]     - cpred[2 * c];
        float dy = cgt[2 * idx + 1] - cpred[2 * c + 1];
        s += sqrtf(dx * dx + dy * dy);
    }
    #pragma unroll
    for (int off = 1; off < 64; off <<= 1) s += __shfl_xor(s, off, 64);
    if (lane == 0) out[2 * N_GT] = s;
}

extern "C" void kernel_launch(void* const* d_in, const int* in_sizes, int n_in,
                              void* d_out, int out_size, void* d_ws, size_t ws_size,
                              hipStream_t stream)
{
    const float* cgt   = (const float*)d_in[0];   // (256, 2)
    const float* cpred = (const float*)d_in[1];   // (1024, 2)
    const float* lgt   = (const float*)d_in[2];   // (256, 91)
    const float* lpred = (const float*)d_in[3];   // (1024, 91)
    float* out  = (float*)d_out;                  // 513 floats

    char* ws = (char*)d_ws;
    float* cost   = (float*)ws;                                  // 1 MB
    float* rowmin = (float*)(ws + (size_t)N_GT * M_PR * 4);      // 1 KB
    int*   rowarg = (int*)  (ws + (size_t)N_GT * M_PR * 4 + 1024);

    cost_kernel<<<N_GT, 256, 0, stream>>>(cgt, cpred, lgt, lpred, cost, rowmin, rowarg);
    lsa_kernel<<<1, 64, 0, stream>>>(cost, rowmin, rowarg, cgt, cpred, out);
}

// Round 9
// 409.037 us; speedup vs baseline: 1.3580x; 1.0317x over previous
//
#include <hip/hip_runtime.h>
#include <math.h>

#define N_GT 256
#define M_PR 1024
#define LG   91
#define CPL  16   // columns per lane (contiguous: lane owns [lane*16, lane*16+16))

// Order-exact monotone map: double -> uint64 (increasing), incl. negatives/inf.
static __device__ __forceinline__ unsigned long long d2key(double x) {
    unsigned long long b = (unsigned long long)__double_as_longlong(x);
    return (b & 0x8000000000000000ull) ? ~b : (b | 0x8000000000000000ull);
}
static __device__ __forceinline__ double key2d(unsigned long long k) {
    unsigned long long b = (k & 0x8000000000000000ull) ? (k ^ 0x8000000000000000ull) : ~k;
    return __longlong_as_double((long long)b);
}

// DPP wave64 min-reduce stage on 96-bit lexicographic key (khi, klo, kcw).
// update_dpp(old=x, src=x): masked/invalid lanes keep old -> identity for min.
#define DPP_STAGE(hi, lo, cw, CTRL, RM, BM) do { \
    unsigned _ohi = (unsigned)__builtin_amdgcn_update_dpp((int)(hi), (int)(hi), CTRL, RM, BM, false); \
    unsigned _olo = (unsigned)__builtin_amdgcn_update_dpp((int)(lo), (int)(lo), CTRL, RM, BM, false); \
    unsigned _ocw = (unsigned)__builtin_amdgcn_update_dpp((int)(cw), (int)(cw), CTRL, RM, BM, false); \
    bool _lt = (_ohi < (hi)) || (_ohi == (hi) && ((_olo < (lo)) || (_olo == (lo) && _ocw < (cw)))); \
    (hi) = _lt ? _ohi : (hi); (lo) = _lt ? _olo : (lo); (cw) = _lt ? _ocw : (cw); \
} while (0)

// ---------------------------------------------------------------------------
// Kernel 1: cost[i][j] = sqrt(|cgt_i - cpred_j|^2) + sum_l |lgt_i - lpred_j|
// F64=1 stores the f32 value widened to double (bit-identical semantics).
// Fused rowmin/rowarg (first-occurrence argmin) for the greedy init.
// ---------------------------------------------------------------------------
template<int F64>
__global__ __launch_bounds__(256) void cost_kernel(
    const float* __restrict__ cgt, const float* __restrict__ cpred,
    const float* __restrict__ lgt, const float* __restrict__ lpred,
    void* __restrict__ costout, float* __restrict__ rowmin, int* __restrict__ rowarg)
{
    __shared__ float sg[LG];
    __shared__ float gx, gy;
    __shared__ float wmin[4];
    __shared__ int   warg[4];
    const int i   = blockIdx.x;
    const int tid = threadIdx.x;
    if (tid < LG) sg[tid] = lgt[i * LG + tid];
    if (tid == 0) { gx = cgt[2 * i]; gy = cgt[2 * i + 1]; }
    __syncthreads();
    float bv = 1e30f; int bj = 0;
    for (int j = tid; j < M_PR; j += 256) {
        float dx = gx - cpred[2 * j];
        float dy = gy - cpred[2 * j + 1];
        float cd = sqrtf(dx * dx + dy * dy);
        const float* lp = lpred + j * LG;
        float s = 0.f;
        #pragma unroll 7
        for (int l = 0; l < LG; ++l) s += fabsf(sg[l] - lp[l]);
        float cv = cd + s;
        if (F64) ((double*)costout)[(size_t)i * M_PR + j] = (double)cv;
        else     ((float*) costout)[(size_t)i * M_PR + j] = cv;
        if (cv < bv) { bv = cv; bj = j; }
    }
    const int lane = tid & 63, wid = tid >> 6;
    #pragma unroll
    for (int off = 1; off < 64; off <<= 1) {
        float ov = __shfl_xor(bv, off, 64);
        int   oj = __shfl_xor(bj, off, 64);
        if (ov < bv || (ov == bv && oj < bj)) { bv = ov; bj = oj; }
    }
    if (lane == 0) { wmin[wid] = bv; warg[wid] = bj; }
    __syncthreads();
    if (tid == 0) {
        for (int w = 1; w < 4; ++w)
            if (wmin[w] < bv || (wmin[w] == bv && warg[w] < bj)) { bv = wmin[w]; bj = warg[w]; }
        rowmin[i] = bv; rowarg[i] = bj;
    }
}

// ---------------------------------------------------------------------------
// Kernel 2: JV LSA (r8-validated semantics: greedy claim u=rowmin, v=0, then
// exact Dijkstra per unmatched row). Single wave, zero barriers in the inner
// loop. Contiguous column ownership (lane owns cols lane*16..lane*16+15) so
// the row fetch is 8x16B. v-poison (-inf) marks settled columns (no usedmask
// test in the scan); markD/vsave side-state in LDS. Absolute-distance form +
// deferred dual flush; DPP min-reduce on an order-exact 96-bit key;
// parallel augmentation apply.
// Output (f32): [0..255]=row, [256..511]=col, [512]=cost.
// ---------------------------------------------------------------------------
template<int F64>
__global__ __launch_bounds__(64) void lsa_kernel(
    const void* __restrict__ costv,
    const float* __restrict__ rowmin, const int* __restrict__ rowarg,
    const float* __restrict__ cgt, const float* __restrict__ cpred,
    float* __restrict__ out)
{
    __shared__ double u[N_GT + 1];
    __shared__ double markD_lds[M_PR + 1];
    __shared__ double vsave_lds[M_PR + 1];
    __shared__ int    p[M_PR + 1];
    __shared__ int    pmin[M_PR + 1];
    __shared__ int    way[M_PR + 1];
    __shared__ int    pathbuf[N_GT + 8];
    __shared__ int    pathlen_s;
    __shared__ int    freeA[N_GT];
    __shared__ int    colarr[N_GT];

    const int lane = threadIdx.x;
    const double NEGINF = -__builtin_inf();
    const double INFD   =  __builtin_inf();

    double v[CPL], A[CPL];
    int    bw[CPL];

    for (int j = lane; j <= M_PR; j += 64) { p[j] = 0; pmin[j] = 0x7FFFFFFF; }
    for (int r = lane; r < N_GT; r += 64) colarr[r] = 0;
    if (lane == 0) u[0] = 0.0;
    #pragma unroll
    for (int k = 0; k < CPL; ++k) { v[k] = 0.0; bw[k] = 0; }
    __syncthreads();

    // ---- greedy claim: row -> its argmin col, smallest row wins ----
    #pragma unroll
    for (int g = 0; g < 4; ++g) {
        int i = g * 64 + lane;                 // 0-based row
        u[i + 1] = (double)rowmin[i];
        atomicMin(&pmin[rowarg[i] + 1], i + 1);
    }
    __syncthreads();
    for (int j = lane + 1; j <= M_PR; j += 64)
        p[j] = (pmin[j] == 0x7FFFFFFF) ? 0 : pmin[j];
    int nfree = 0;
    #pragma unroll
    for (int g = 0; g < 4; ++g) {
        int i = g * 64 + lane;
        bool um = (pmin[rowarg[i] + 1] != i + 1);
        unsigned long long mask = __ballot(um);
        int pos = nfree + __popcll(mask & ((1ull << lane) - 1ull));
        if (um) freeA[pos] = i + 1;            // 1-based row
        nfree += __popcll(mask);
    }
    __syncthreads();

    const int colbase = lane * CPL;            // 0-based first owned column

    // ---- shortest augmenting path per free row ----
    for (int t = 0; t < nfree; ++t) {
        const int i = freeA[t];
        #pragma unroll
        for (int k = 0; k < CPL; ++k) A[k] = 1e18;
        unsigned usedmask = 0u;
        double D  = 0.0;
        int    j0 = 0;
        int    i0 = i;
        while (true) {
            // issue row loads first (overlap with LDS u read + settle work)
            double cd[CPL];
            if (F64) {
                const double2* rp = (const double2*)((const double*)costv
                                    + (size_t)(i0 - 1) * M_PR + colbase);
                #pragma unroll
                for (int h = 0; h < CPL / 2; ++h) {
                    double2 tv = rp[h];
                    cd[2 * h] = tv.x; cd[2 * h + 1] = tv.y;
                }
            } else {
                const float4* rp = (const float4*)((const float*)costv
                                   + (size_t)(i0 - 1) * M_PR + colbase);
                #pragma unroll
                for (int h = 0; h < CPL / 4; ++h) {
                    float4 tv = rp[h];
                    cd[4 * h]     = (double)tv.x; cd[4 * h + 1] = (double)tv.y;
                    cd[4 * h + 2] = (double)tv.z; cd[4 * h + 3] = (double)tv.w;
                }
            }
            double ui = u[i0];                  // LDS broadcast (search-start value)

            // settle previous winner j0 (uniform): owner lane poisons v, saves state
            if (j0 > 0) {
                const int olane = (j0 - 1) >> 4;
                const int okk   = (j0 - 1) & 15;
                if (olane == lane) {
                    markD_lds[j0] = D;
                    #pragma unroll
                    for (int k = 0; k < CPL; ++k) {
                        if (k == okk) {
                            vsave_lds[j0] = v[k];
                            v[k] = NEGINF;      // cur = +inf henceforth
                            A[k] = INFD;        // never wins tournament
                            usedmask |= (1u << k);
                        }
                    }
                }
            }
            double base2 = ui - D;              // cur_abs = c - base2 - v[k]

            double   bA  = INFD;
            unsigned bcw = 0xFFFFFFFFu;
            #pragma unroll
            for (int k = 0; k < CPL; ++k) {
                double cur = cd[k] - base2 - v[k];
                bool upd = (cur < A[k]);        // settled: cur=+inf -> false
                A[k]  = upd ? cur : A[k];
                bw[k] = upd ? j0  : bw[k];
                unsigned cwk = ((unsigned)(colbase + k + 1) << 11) | (unsigned)bw[k];
                bool tk = (A[k] < bA);          // strict: smallest col kept on tie
                bA  = tk ? A[k] : bA;
                bcw = tk ? cwk  : bcw;
            }
            // order-exact 96-bit DPP min-reduce -> lane 63
            unsigned long long key = d2key(bA);
            unsigned khi = (unsigned)(key >> 32);
            unsigned klo = (unsigned)(key & 0xFFFFFFFFull);
            unsigned kcw = bcw;
            DPP_STAGE(khi, klo, kcw, 0x111, 0xf, 0xf);  // row_shr:1
            DPP_STAGE(khi, klo, kcw, 0x112, 0xf, 0xf);  // row_shr:2
            DPP_STAGE(khi, klo, kcw, 0x114, 0xf, 0xe);  // row_shr:4
            DPP_STAGE(khi, klo, kcw, 0x118, 0xf, 0xc);  // row_shr:8
            DPP_STAGE(khi, klo, kcw, 0x142, 0xa, 0xf);  // row_bcast:15
            DPP_STAGE(khi, klo, kcw, 0x143, 0xc, 0xf);  // row_bcast:31
            unsigned rhi = (unsigned)__builtin_amdgcn_readlane((int)khi, 63);
            unsigned rlo = (unsigned)__builtin_amdgcn_readlane((int)klo, 63);
            unsigned rcw = (unsigned)__builtin_amdgcn_readlane((int)kcw, 63);
            D = key2d(((unsigned long long)rhi << 32) | (unsigned long long)rlo);
            int j1 = (int)(rcw >> 11);
            int w1 = (int)(rcw & 2047u);
            if (lane == 0) way[j1] = w1;
            int pj = p[j1];                     // LDS broadcast
            j0 = j1;
            if (pj == 0) break;                 // reached a free column
            i0 = pj;
        }
        // ---- deferred dual flush (pre-augmentation p) ----
        if (lane == 0) u[i] += D;               // virtual col 0: markD = 0
        #pragma unroll
        for (int k = 0; k < CPL; ++k) {
            if ((usedmask >> k) & 1u) {
                const int col = colbase + k + 1;
                double adj = D - markD_lds[col];
                v[k] = vsave_lds[col] - adj;    // restore + adjust
                int r = p[col];                 // distinct rows, no race
                u[r] += adj;
            }
        }
        __syncthreads();
        // ---- augmentation: collect path, then parallel apply (old reads) ----
        if (lane == 0) {
            int L = 0, jj = j0;
            while (jj != 0) { pathbuf[L++] = jj; jj = way[jj]; }
            pathlen_s = L;
        }
        __syncthreads();
        const int L = pathlen_s;                // L <= 257
        int d0=-1,s0=0,d1=-1,s1=0,d2=-1,s2=0,d3=-1,s3=0,d4=-1,s4=0;
        { int tt = lane;       if (tt < L) { d0 = pathbuf[tt]; s0 = (tt == L-1) ? i : p[pathbuf[tt+1]]; } }
        { int tt = lane +  64; if (tt < L) { d1 = pathbuf[tt]; s1 = (tt == L-1) ? i : p[pathbuf[tt+1]]; } }
        { int tt = lane + 128; if (tt < L) { d2 = pathbuf[tt]; s2 = (tt == L-1) ? i : p[pathbuf[tt+1]]; } }
        { int tt = lane + 192; if (tt < L) { d3 = pathbuf[tt]; s3 = (tt == L-1) ? i : p[pathbuf[tt+1]]; } }
        { int tt = lane + 256; if (tt < L) { d4 = pathbuf[tt]; s4 = (tt == L-1) ? i : p[pathbuf[tt+1]]; } }
        __syncthreads();
        if (d0 >= 0) p[d0] = s0;
        if (d1 >= 0) p[d1] = s1;
        if (d2 >= 0) p[d2] = s2;
        if (d3 >= 0) p[d3] = s3;
        if (d4 >= 0) p[d4] = s4;
        __syncthreads();
    }

    // ---- gather + outputs (lane-stride mapping: conflict-free p reads) ----
    #pragma unroll
    for (int k = 0; k < CPL; ++k) {
        int j  = lane + 1 + 64 * k;
        int pr = p[j];
        if (pr > 0) colarr[pr - 1] = j - 1;
    }
    __syncthreads();

    for (int idx = lane; idx < N_GT; idx += 64) {
        out[idx]        = (float)idx;
        out[N_GT + idx] = (float)colarr[idx];
    }
    float s = 0.f;
    for (int idx = lane; idx < N_GT; idx += 64) {
        int c = colarr[idx];
        c = (c < 0) ? 0 : (c >= M_PR ? M_PR - 1 : c);
        float dx = cgt[2 * idx]     - cpred[2 * c];
        float dy = cgt[2 * idx + 1] - cpred[2 * c + 1];
        s += sqrtf(dx * dx + dy * dy);
    }
    #pragma unroll
    for (int off = 1; off < 64; off <<= 1) s += __shfl_xor(s, off, 64);
    if (lane == 0) out[2 * N_GT] = s;
}

extern "C" void kernel_launch(void* const* d_in, const int* in_sizes, int n_in,
                              void* d_out, int out_size, void* d_ws, size_t ws_size,
                              hipStream_t stream)
{
    const float* cgt   = (const float*)d_in[0];   // (256, 2)
    const float* cpred = (const float*)d_in[1];   // (1024, 2)
    const float* lgt   = (const float*)d_in[2];   // (256, 91)
    const float* lpred = (const float*)d_in[3];   // (1024, 91)
    float* out  = (float*)d_out;                  // 513 floats

    char* ws = (char*)d_ws;
    const size_t mat64 = (size_t)N_GT * M_PR * 8;           // 2 MB
    const size_t mat32 = (size_t)N_GT * M_PR * 4;           // 1 MB

    if (ws_size >= mat64 + 4096) {
        void*  cost   = (void*)ws;
        float* rowmin = (float*)(ws + mat64);
        int*   rowarg = (int*)  (ws + mat64 + 1024);
        cost_kernel<1><<<N_GT, 256, 0, stream>>>(cgt, cpred, lgt, lpred, cost, rowmin, rowarg);
        lsa_kernel<1><<<1, 64, 0, stream>>>(cost, rowmin, rowarg, cgt, cpred, out);
    } else {
        void*  cost   = (void*)ws;
        float* rowmin = (float*)(ws + mat32);
        int*   rowarg = (int*)  (ws + mat32 + 1024);
        cost_kernel<0><<<N_GT, 256, 0, stream>>>(cgt, cpred, lgt, lpred, cost, rowmin, rowarg);
        lsa_kernel<0><<<1, 64, 0, stream>>>(cost, rowmin, rowarg, cgt, cpred, out);
    }
}